// Round 2
// baseline (481.089 us; speedup 1.0000x reference)
//
#include <hip/hip_runtime.h>
#include <hip/hip_bf16.h>

#define IN_CH 128
#define HID   64
#define N_REL 8

using bf16x8 = __attribute__((ext_vector_type(8))) short;  // 8 bf16 (4 VGPRs)
using f32x4  = __attribute__((ext_vector_type(4))) float;

// float -> bf16 bits, round-to-nearest-even (finite inputs)
__device__ __forceinline__ short f2bf(float f) {
    unsigned int u = __float_as_uint(f);
    u += 0x7fffu + ((u >> 16) & 1u);
    return (short)(u >> 16);
}
__device__ __forceinline__ float bf2f(unsigned short b) {
    return __uint_as_float(((unsigned int)b) << 16);
}

// ---------------------------------------------------------------------------
// proj (MFMA): for r in 0..7: xp[r][n][h] = bf16( x[n]·W_rel[r][h] + b_rel[r][h] )
//              r == 8:        agg[n][h]   = x[n]·W_self[h]            (fp32)
// Block = 64 nodes, 4 waves; wave w owns nodes [w*16, w*16+16).
// A-fragments (x rows, bf16) loaded ONCE per wave, reused for all 9 r.
// Weights streamed from L2 (294 KB total, fully resident).
// ---------------------------------------------------------------------------
__global__ __launch_bounds__(256) void proj_mfma_kernel(
    const float* __restrict__ x,        // [N,128]
    const float* __restrict__ W_rel,    // [8,64,128]
    const float* __restrict__ b_rel,    // [8,64]
    const float* __restrict__ W_self,   // [64,128]
    unsigned short* __restrict__ xp,    // [8,N,64] bf16 bits
    float* __restrict__ agg,            // [N,64] fp32
    int N)
{
    const int tid  = threadIdx.x;
    const int wave = tid >> 6;
    const int lane = tid & 63;
    const int l16  = lane & 15;
    const int quad = lane >> 4;
    const int nbase = blockIdx.x * 64 + wave * 16;

    // A fragments: 4 k-steps of 32; lane holds x[nbase+l16][s*32+quad*8 .. +7]
    bf16x8 afrag[4];
    const int anode = nbase + l16;
    #pragma unroll
    for (int s = 0; s < 4; ++s) {
        float v[8] = {};
        if (anode < N) {
            const float* p = x + (size_t)anode * IN_CH + s * 32 + quad * 8;
            float4 u0 = *(const float4*)p;
            float4 u1 = *(const float4*)(p + 4);
            v[0]=u0.x; v[1]=u0.y; v[2]=u0.z; v[3]=u0.w;
            v[4]=u1.x; v[5]=u1.y; v[6]=u1.z; v[7]=u1.w;
        }
        bf16x8 a;
        #pragma unroll
        for (int j = 0; j < 8; ++j) a[j] = f2bf(v[j]);
        afrag[s] = a;
    }

    for (int r = 0; r <= N_REL; ++r) {
        const float* W = (r < N_REL) ? (W_rel + (size_t)r * HID * IN_CH) : W_self;
        f32x4 acc[4] = {{0.f,0.f,0.f,0.f},{0.f,0.f,0.f,0.f},
                        {0.f,0.f,0.f,0.f},{0.f,0.f,0.f,0.f}};
        #pragma unroll
        for (int s = 0; s < 4; ++s) {
            #pragma unroll
            for (int t = 0; t < 4; ++t) {
                // B fragment: lane holds W[t*16+l16][s*32+quad*8 .. +7]
                const float* p = W + (size_t)(t * 16 + l16) * IN_CH + s * 32 + quad * 8;
                float4 u0 = *(const float4*)p;
                float4 u1 = *(const float4*)(p + 4);
                bf16x8 b;
                b[0]=f2bf(u0.x); b[1]=f2bf(u0.y); b[2]=f2bf(u0.z); b[3]=f2bf(u0.w);
                b[4]=f2bf(u1.x); b[5]=f2bf(u1.y); b[6]=f2bf(u1.z); b[7]=f2bf(u1.w);
                acc[t] = __builtin_amdgcn_mfma_f32_16x16x32_bf16(afrag[s], b, acc[t], 0, 0, 0);
            }
        }
        // epilogue: D[node=quad*4+i][h=t*16+l16]
        #pragma unroll
        for (int t = 0; t < 4; ++t) {
            const int h = t * 16 + l16;
            float bias = (r < N_REL) ? b_rel[r * HID + h] : 0.f;
            #pragma unroll
            for (int i = 0; i < 4; ++i) {
                const int node = nbase + quad * 4 + i;
                if (node < N) {
                    float val = acc[t][i] + bias;
                    if (r < N_REL)
                        xp[((size_t)r * N + node) * HID + h] = (unsigned short)f2bf(val);
                    else
                        agg[(size_t)node * HID + h] = val;
                }
            }
        }
    }
}

// ---------------------------------------------------------------------------
// edge scatter: wave per edge; lane h adds bf16 xp[t][src][h] (bias pre-folded)
// into agg[dst][h] with device-scope atomics.
// ---------------------------------------------------------------------------
__global__ __launch_bounds__(256) void edge_kernel(
    const int* __restrict__ edge_index,        // [2,E]
    const int* __restrict__ edge_type,         // [E]
    const unsigned short* __restrict__ xp,     // [8,N,64] bf16 bits
    float* __restrict__ agg,                   // [N,64]
    int E, int N)
{
    long long gid = (long long)blockIdx.x * blockDim.x + threadIdx.x;
    int e = (int)(gid >> 6);
    int h = (int)(gid & 63);
    if (e >= E) return;
    int src = edge_index[e];
    int dst = edge_index[E + e];
    int t   = edge_type[e];
    float m = bf2f(xp[((size_t)t * N + src) * HID + h]);
    atomicAdd(agg + (size_t)dst * HID + h, m);
}

// ---------------------------------------------------------------------------
// finalize: wave per node: out[n] = W_out . relu(agg[n] + b_self) + b_out
// ---------------------------------------------------------------------------
__global__ __launch_bounds__(256) void finalize_kernel(
    const float* __restrict__ agg,
    const float* __restrict__ b_self,
    const float* __restrict__ W_out,
    const float* __restrict__ b_out,
    float* __restrict__ out,
    int N)
{
    long long gid = (long long)blockIdx.x * blockDim.x + threadIdx.x;
    int n = (int)(gid >> 6);
    int h = (int)(gid & 63);
    if (n >= N) return;
    float v = agg[(size_t)n * HID + h] + b_self[h];
    v = fmaxf(v, 0.f);
    float p = v * W_out[h];
    #pragma unroll
    for (int off = 32; off > 0; off >>= 1)
        p += __shfl_down(p, off, 64);
    if (h == 0) out[n] = p + b_out[0];
}

extern "C" void kernel_launch(void* const* d_in, const int* in_sizes, int n_in,
                              void* d_out, int out_size, void* d_ws, size_t ws_size,
                              hipStream_t stream)
{
    const float* x          = (const float*)d_in[0];
    const int*   edge_index = (const int*)  d_in[1];
    const int*   edge_type  = (const int*)  d_in[2];
    const float* W_rel      = (const float*)d_in[3];
    const float* b_rel      = (const float*)d_in[4];
    const float* W_self     = (const float*)d_in[5];
    const float* b_self     = (const float*)d_in[6];
    const float* W_out      = (const float*)d_in[7];
    const float* b_out      = (const float*)d_in[8];
    float* out = (float*)d_out;

    const int N = in_sizes[0] / IN_CH;   // 100000
    const int E = in_sizes[2];           // 600000

    unsigned short* xp = (unsigned short*)d_ws;            // [8,N,64] bf16, 102.4 MB
    float* agg = (float*)(xp + (size_t)N_REL * N * HID);   // [N,64] fp32, 25.6 MB

    // 1) projections via bf16 MFMA (r==8 initializes agg; b_rel folded into xp)
    int pblocks = (N + 63) / 64;
    proj_mfma_kernel<<<pblocks, 256, 0, stream>>>(x, W_rel, b_rel, W_self,
                                                  xp, agg, N);

    // 2) edge gather + scatter-add
    long long ethreads = (long long)E * 64;
    int eblocks = (int)((ethreads + 255) / 256);
    edge_kernel<<<eblocks, 256, 0, stream>>>(edge_index, edge_type, xp,
                                             agg, E, N);

    // 3) relu + output projection
    long long fthreads = (long long)N * 64;
    int fblocks = (int)((fthreads + 255) / 256);
    finalize_kernel<<<fblocks, 256, 0, stream>>>(agg, b_self, W_out, b_out,
                                                 out, N);
}

// Round 3
// 307.101 us; speedup vs baseline: 1.5666x; 1.5666x over previous
//
#include <hip/hip_runtime.h>
#include <hip/hip_bf16.h>

#define IN_CH 128
#define HID   64
#define N_REL 8

using bf16x8 = __attribute__((ext_vector_type(8))) short;  // 8 bf16 (4 VGPRs)
using f32x4  = __attribute__((ext_vector_type(4))) float;

// float -> bf16 bits, round-to-nearest-even (finite inputs)
__device__ __forceinline__ short f2bf(float f) {
    unsigned int u = __float_as_uint(f);
    u += 0x7fffu + ((u >> 16) & 1u);
    return (short)(u >> 16);
}
__device__ __forceinline__ float bf2f(unsigned short b) {
    return __uint_as_float(((unsigned int)b) << 16);
}

// ---------------------------------------------------------------------------
// pack_w: rearrange the 9 weight matrices (8 rel + self) into bf16 MFMA
// B-fragment order so proj can load fragments with coalesced dwordx4:
//   wpk[((r*16 + s*4 + t)*64 + lane)*8 + j]
//     = bf16( W_r[t*16 + (lane&15)][s*32 + (lane>>4)*8 + j] )
// 9216 lane-fragments total (147 KB) — L2-resident for the whole proj pass.
// ---------------------------------------------------------------------------
__global__ __launch_bounds__(256) void pack_w_kernel(
    const float* __restrict__ W_rel,   // [8,64,128]
    const float* __restrict__ W_self,  // [64,128]
    unsigned short* __restrict__ wpk)  // [9*16*64*8]
{
    int gid = blockIdx.x * 256 + threadIdx.x;
    if (gid >= 9 * 16 * 64) return;
    int r    = gid >> 10;          // /1024
    int f    = (gid >> 6) & 15;    // s*4 + t
    int lane = gid & 63;
    int s = f >> 2, t = f & 3;
    int row = t * 16 + (lane & 15);
    int col = s * 32 + (lane >> 4) * 8;
    const float* W = (r < N_REL) ? (W_rel + (size_t)r * HID * IN_CH) : W_self;
    const float* p = W + (size_t)row * IN_CH + col;
    float4 u0 = *(const float4*)p;
    float4 u1 = *(const float4*)(p + 4);
    bf16x8 b;
    b[0]=f2bf(u0.x); b[1]=f2bf(u0.y); b[2]=f2bf(u0.z); b[3]=f2bf(u0.w);
    b[4]=f2bf(u1.x); b[5]=f2bf(u1.y); b[6]=f2bf(u1.z); b[7]=f2bf(u1.w);
    *(bf16x8*)(wpk + (size_t)gid * 8) = b;
}

// ---------------------------------------------------------------------------
// proj (MFMA): for r in 0..7: xp[r][n][h] = bf16( x[n]·W_rel[r][h] + b_rel[r][h] )
//              r == 8:        agg[n][h]   = x[n]·W_self[h]            (fp32)
// Block = 128 nodes, 4 waves; wave owns 32 nodes (2 sub-tiles of 16).
// A-fragments loaded once, reused for all 9 relations. B-fragments come from
// the pre-packed wpk via fully-coalesced dwordx4 (64 lanes x 16 B contiguous).
// ---------------------------------------------------------------------------
__global__ __launch_bounds__(256) void proj_mfma_kernel(
    const float* __restrict__ x,        // [N,128]
    const unsigned short* __restrict__ wpk,
    const float* __restrict__ b_rel,    // [8,64]
    unsigned short* __restrict__ xp,    // [8,N,64] bf16 bits
    float* __restrict__ agg,            // [N,64] fp32
    int N)
{
    const int tid  = threadIdx.x;
    const int wave = tid >> 6;
    const int lane = tid & 63;
    const int l16  = lane & 15;
    const int quad = lane >> 4;
    const int nwb  = blockIdx.x * 128 + wave * 32;   // wave's 32-node base

    // A fragments: af[sub][s] = x[nwb+sub*16+l16][s*32+quad*8 .. +7] as bf16
    bf16x8 af[2][4];
    #pragma unroll
    for (int sub = 0; sub < 2; ++sub) {
        const int anode = nwb + sub * 16 + l16;
        #pragma unroll
        for (int s = 0; s < 4; ++s) {
            float v[8] = {};
            if (anode < N) {
                const float* p = x + (size_t)anode * IN_CH + s * 32 + quad * 8;
                float4 u0 = *(const float4*)p;
                float4 u1 = *(const float4*)(p + 4);
                v[0]=u0.x; v[1]=u0.y; v[2]=u0.z; v[3]=u0.w;
                v[4]=u1.x; v[5]=u1.y; v[6]=u1.z; v[7]=u1.w;
            }
            bf16x8 a;
            #pragma unroll
            for (int j = 0; j < 8; ++j) a[j] = f2bf(v[j]);
            af[sub][s] = a;
        }
    }

    const bf16x8* wv = (const bf16x8*)wpk;

    #pragma unroll 1
    for (int r = 0; r <= N_REL; ++r) {
        f32x4 acc[2][4];
        #pragma unroll
        for (int sub = 0; sub < 2; ++sub)
            #pragma unroll
            for (int t = 0; t < 4; ++t)
                acc[sub][t] = (f32x4){0.f, 0.f, 0.f, 0.f};

        #pragma unroll
        for (int s = 0; s < 4; ++s) {
            // 4 coalesced fragment loads (1 KB per wave each), all in flight
            bf16x8 bs[4];
            #pragma unroll
            for (int t = 0; t < 4; ++t)
                bs[t] = wv[(size_t)((r * 16 + s * 4 + t) * 64) + lane];
            #pragma unroll
            for (int sub = 0; sub < 2; ++sub)
                #pragma unroll
                for (int t = 0; t < 4; ++t)
                    acc[sub][t] = __builtin_amdgcn_mfma_f32_16x16x32_bf16(
                        af[sub][s], bs[t], acc[sub][t], 0, 0, 0);
        }

        // epilogue: D[node = sub*16 + quad*4 + i][h = t*16 + l16]
        #pragma unroll
        for (int t = 0; t < 4; ++t) {
            const int h = t * 16 + l16;
            const float bias = (r < N_REL) ? b_rel[r * HID + h] : 0.f;
            #pragma unroll
            for (int sub = 0; sub < 2; ++sub) {
                #pragma unroll
                for (int i = 0; i < 4; ++i) {
                    const int node = nwb + sub * 16 + quad * 4 + i;
                    if (node < N) {
                        float val = acc[sub][t][i] + bias;
                        if (r < N_REL)
                            xp[((size_t)r * N + node) * HID + h] =
                                (unsigned short)f2bf(val);
                        else
                            agg[(size_t)node * HID + h] = val;
                    }
                }
            }
        }
    }
}

// ---------------------------------------------------------------------------
// edge scatter: wave per edge; lane h adds bf16 xp[t][src][h] (bias pre-folded)
// into agg[dst][h] with device-scope atomics.
// ---------------------------------------------------------------------------
__global__ __launch_bounds__(256) void edge_kernel(
    const int* __restrict__ edge_index,        // [2,E]
    const int* __restrict__ edge_type,         // [E]
    const unsigned short* __restrict__ xp,     // [8,N,64] bf16 bits
    float* __restrict__ agg,                   // [N,64]
    int E, int N)
{
    long long gid = (long long)blockIdx.x * blockDim.x + threadIdx.x;
    int e = (int)(gid >> 6);
    int h = (int)(gid & 63);
    if (e >= E) return;
    int src = edge_index[e];
    int dst = edge_index[E + e];
    int t   = edge_type[e];
    float m = bf2f(xp[((size_t)t * N + src) * HID + h]);
    atomicAdd(agg + (size_t)dst * HID + h, m);
}

// ---------------------------------------------------------------------------
// finalize: wave per node: out[n] = W_out . relu(agg[n] + b_self) + b_out
// ---------------------------------------------------------------------------
__global__ __launch_bounds__(256) void finalize_kernel(
    const float* __restrict__ agg,
    const float* __restrict__ b_self,
    const float* __restrict__ W_out,
    const float* __restrict__ b_out,
    float* __restrict__ out,
    int N)
{
    long long gid = (long long)blockIdx.x * blockDim.x + threadIdx.x;
    int n = (int)(gid >> 6);
    int h = (int)(gid & 63);
    if (n >= N) return;
    float v = agg[(size_t)n * HID + h] + b_self[h];
    v = fmaxf(v, 0.f);
    float p = v * W_out[h];
    #pragma unroll
    for (int off = 32; off > 0; off >>= 1)
        p += __shfl_down(p, off, 64);
    if (h == 0) out[n] = p + b_out[0];
}

extern "C" void kernel_launch(void* const* d_in, const int* in_sizes, int n_in,
                              void* d_out, int out_size, void* d_ws, size_t ws_size,
                              hipStream_t stream)
{
    const float* x          = (const float*)d_in[0];
    const int*   edge_index = (const int*)  d_in[1];
    const int*   edge_type  = (const int*)  d_in[2];
    const float* W_rel      = (const float*)d_in[3];
    const float* b_rel      = (const float*)d_in[4];
    const float* W_self     = (const float*)d_in[5];
    const float* b_self     = (const float*)d_in[6];
    const float* W_out      = (const float*)d_in[7];
    const float* b_out      = (const float*)d_in[8];
    float* out = (float*)d_out;

    const int N = in_sizes[0] / IN_CH;   // 100000
    const int E = in_sizes[2];           // 600000

    unsigned short* xp  = (unsigned short*)d_ws;              // [8,N,64] bf16, 102.4 MB
    float* agg = (float*)(xp + (size_t)N_REL * N * HID);      // [N,64] fp32, 25.6 MB
    unsigned short* wpk = (unsigned short*)(agg + (size_t)N * HID);  // 147 KB

    // 0) pack weights into MFMA fragment order (bf16)
    pack_w_kernel<<<36, 256, 0, stream>>>(W_rel, W_self, wpk);

    // 1) projections via bf16 MFMA (r==8 initializes agg; b_rel folded into xp)
    int pblocks = (N + 127) / 128;
    proj_mfma_kernel<<<pblocks, 256, 0, stream>>>(x, wpk, b_rel, xp, agg, N);

    // 2) edge gather + scatter-add
    long long ethreads = (long long)E * 64;
    int eblocks = (int)((ethreads + 255) / 256);
    edge_kernel<<<eblocks, 256, 0, stream>>>(edge_index, edge_type, xp,
                                             agg, E, N);

    // 3) relu + output projection
    long long fthreads = (long long)N * 64;
    int fblocks = (int)((fthreads + 255) / 256);
    finalize_kernel<<<fblocks, 256, 0, stream>>>(agg, b_self, W_out, b_out,
                                                 out, N);
}

// Round 4
// 300.004 us; speedup vs baseline: 1.6036x; 1.0237x over previous
//
#include <hip/hip_runtime.h>
#include <hip/hip_bf16.h>

#define IN_CH 128
#define HID   64
#define N_REL 8

using bf16x8 = __attribute__((ext_vector_type(8))) short;  // 8 bf16 (4 VGPRs)
using f32x4  = __attribute__((ext_vector_type(4))) float;

// float -> bf16 bits, round-to-nearest-even (finite inputs)
__device__ __forceinline__ short f2bf(float f) {
    unsigned int u = __float_as_uint(f);
    u += 0x7fffu + ((u >> 16) & 1u);
    return (short)(u >> 16);
}
__device__ __forceinline__ float bf2f(unsigned short b) {
    return __uint_as_float(((unsigned int)b) << 16);
}

// ---------------------------------------------------------------------------
// pack_w: rearrange the 9 weight matrices (8 rel + self) into bf16 MFMA
// fragment order (operand layout [row=lane&15][k=(lane>>4)*8+j]):
//   wpk[((r*16 + s*4 + t)*64 + lane)*8 + j]
//     = bf16( W_r[t*16 + (lane&15)][s*32 + (lane>>4)*8 + j] )
// 147 KB total — L2-resident for the whole proj pass.
// ---------------------------------------------------------------------------
__global__ __launch_bounds__(256) void pack_w_kernel(
    const float* __restrict__ W_rel,   // [8,64,128]
    const float* __restrict__ W_self,  // [64,128]
    unsigned short* __restrict__ wpk)  // [9*16*64*8]
{
    int gid = blockIdx.x * 256 + threadIdx.x;
    if (gid >= 9 * 16 * 64) return;
    int r    = gid >> 10;
    int f    = (gid >> 6) & 15;    // s*4 + t
    int lane = gid & 63;
    int s = f >> 2, t = f & 3;
    int row = t * 16 + (lane & 15);
    int col = s * 32 + (lane >> 4) * 8;
    const float* W = (r < N_REL) ? (W_rel + (size_t)r * HID * IN_CH) : W_self;
    const float* p = W + (size_t)row * IN_CH + col;
    float4 u0 = *(const float4*)p;
    float4 u1 = *(const float4*)(p + 4);
    bf16x8 b;
    b[0]=f2bf(u0.x); b[1]=f2bf(u0.y); b[2]=f2bf(u0.z); b[3]=f2bf(u0.w);
    b[4]=f2bf(u1.x); b[5]=f2bf(u1.y); b[6]=f2bf(u1.z); b[7]=f2bf(u1.w);
    *(bf16x8*)(wpk + (size_t)gid * 8) = b;
}

// ---------------------------------------------------------------------------
// proj (MFMA, swapped operands A=W, B=x):
//   r<8:  xp[r][n][h] = bf16( x[n]·W_rel[r][h] + b_rel[r][h] )
//   r==8: selfp[n][h] = x[n]·W_self[h]                         (fp32)
// D layout: node = lane&15 (B-rows), h = t*16 + quad*4 + reg (A-rows)
// -> each lane holds 4 CONSECUTIVE h per node: 8 B packed bf16 stores.
// Block = 128 nodes, 4 waves; wave owns 32 nodes (2 sub-tiles of 16).
// ---------------------------------------------------------------------------
__global__ __launch_bounds__(256) void proj_mfma_kernel(
    const float* __restrict__ x,        // [N,128]
    const unsigned short* __restrict__ wpk,
    const float* __restrict__ b_rel,    // [8,64]
    unsigned short* __restrict__ xp,    // [8,N,64] bf16 bits
    float* __restrict__ selfp,          // [N,64] fp32
    int N)
{
    const int tid  = threadIdx.x;
    const int wave = tid >> 6;
    const int lane = tid & 63;
    const int l16  = lane & 15;
    const int quad = lane >> 4;
    const int nwb  = blockIdx.x * 128 + wave * 32;   // wave's 32-node base

    // x fragments (B operand): xf[sub][s] = x[nwb+sub*16+l16][s*32+quad*8..+7]
    bf16x8 xf[2][4];
    #pragma unroll
    for (int sub = 0; sub < 2; ++sub) {
        const int anode = nwb + sub * 16 + l16;
        #pragma unroll
        for (int s = 0; s < 4; ++s) {
            float v[8] = {};
            if (anode < N) {
                const float* p = x + (size_t)anode * IN_CH + s * 32 + quad * 8;
                float4 u0 = *(const float4*)p;
                float4 u1 = *(const float4*)(p + 4);
                v[0]=u0.x; v[1]=u0.y; v[2]=u0.z; v[3]=u0.w;
                v[4]=u1.x; v[5]=u1.y; v[6]=u1.z; v[7]=u1.w;
            }
            bf16x8 a;
            #pragma unroll
            for (int j = 0; j < 8; ++j) a[j] = f2bf(v[j]);
            xf[sub][s] = a;
        }
    }

    const bf16x8* wv = (const bf16x8*)wpk;

    #pragma unroll 1
    for (int r = 0; r <= N_REL; ++r) {
        f32x4 acc[2][4];
        #pragma unroll
        for (int sub = 0; sub < 2; ++sub)
            #pragma unroll
            for (int t = 0; t < 4; ++t)
                acc[sub][t] = (f32x4){0.f, 0.f, 0.f, 0.f};

        #pragma unroll
        for (int s = 0; s < 4; ++s) {
            bf16x8 ws[4];
            #pragma unroll
            for (int t = 0; t < 4; ++t)
                ws[t] = wv[(size_t)((r * 16 + s * 4 + t) * 64) + lane];
            #pragma unroll
            for (int sub = 0; sub < 2; ++sub)
                #pragma unroll
                for (int t = 0; t < 4; ++t)
                    acc[sub][t] = __builtin_amdgcn_mfma_f32_16x16x32_bf16(
                        ws[t], xf[sub][s], acc[sub][t], 0, 0, 0);
        }

        // epilogue: lane holds node = nwb+sub*16+l16, h = t*16+quad*4+i
        #pragma unroll
        for (int t = 0; t < 4; ++t) {
            const int hb = t * 16 + quad * 4;
            float4 bias = make_float4(0.f, 0.f, 0.f, 0.f);
            if (r < N_REL) bias = *(const float4*)(b_rel + r * HID + hb);
            #pragma unroll
            for (int sub = 0; sub < 2; ++sub) {
                const int node = nwb + sub * 16 + l16;
                if (node < N) {
                    if (r < N_REL) {
                        ushort4 u;
                        u.x = (unsigned short)f2bf(acc[sub][t][0] + bias.x);
                        u.y = (unsigned short)f2bf(acc[sub][t][1] + bias.y);
                        u.z = (unsigned short)f2bf(acc[sub][t][2] + bias.z);
                        u.w = (unsigned short)f2bf(acc[sub][t][3] + bias.w);
                        *(ushort4*)(xp + ((size_t)r * N + node) * HID + hb) = u;
                    } else {
                        float4 o = make_float4(acc[sub][t][0], acc[sub][t][1],
                                               acc[sub][t][2], acc[sub][t][3]);
                        *(float4*)(selfp + (size_t)node * HID + hb) = o;
                    }
                }
            }
        }
    }
}

// ---------------------------------------------------------------------------
// CSR build: histogram of dst -> exclusive scan -> fill packed edge list.
// ---------------------------------------------------------------------------
__global__ __launch_bounds__(256) void hist_kernel(
    const int* __restrict__ edge_index, int* __restrict__ cnt, int E)
{
    int e = blockIdx.x * 256 + threadIdx.x;
    if (e < E) atomicAdd(&cnt[edge_index[E + e]], 1);
}

#define SCAN_E 1024   // elements per scan block (256 threads x 4)

__global__ __launch_bounds__(256) void scan_blocksum_kernel(
    const int* __restrict__ cnt, int* __restrict__ bsum, int N)
{
    __shared__ int s[256];
    int tid = threadIdx.x;
    int base = blockIdx.x * SCAN_E + tid * 4;
    int v = 0;
    #pragma unroll
    for (int j = 0; j < 4; ++j)
        if (base + j < N) v += cnt[base + j];
    s[tid] = v; __syncthreads();
    for (int off = 128; off > 0; off >>= 1) {
        if (tid < off) s[tid] += s[tid + off];
        __syncthreads();
    }
    if (tid == 0) bsum[blockIdx.x] = s[0];
}

__global__ __launch_bounds__(128) void scan_partials_kernel(
    int* __restrict__ bsum, int NB)   // NB <= 128
{
    __shared__ int s[128];
    int tid = threadIdx.x;
    int own = (tid < NB) ? bsum[tid] : 0;
    s[tid] = own; __syncthreads();
    for (int off = 1; off < 128; off <<= 1) {
        int v = (tid >= off) ? s[tid - off] : 0;
        __syncthreads();
        s[tid] += v;
        __syncthreads();
    }
    if (tid < NB) bsum[tid] = s[tid] - own;   // exclusive
}

__global__ __launch_bounds__(256) void scan_write_kernel(
    const int* __restrict__ cnt, const int* __restrict__ bsumx,
    int* __restrict__ offsets, int* __restrict__ cursor, int N)
{
    __shared__ int s[256];
    int tid = threadIdx.x;
    int base = blockIdx.x * SCAN_E + tid * 4;
    int v[4]; int sum = 0;
    #pragma unroll
    for (int j = 0; j < 4; ++j) {
        v[j] = (base + j < N) ? cnt[base + j] : 0;
        sum += v[j];
    }
    s[tid] = sum; __syncthreads();
    for (int off = 1; off < 256; off <<= 1) {
        int w = (tid >= off) ? s[tid - off] : 0;
        __syncthreads();
        s[tid] += w;
        __syncthreads();
    }
    int running = bsumx[blockIdx.x] + s[tid] - sum;   // exclusive up to base
    #pragma unroll
    for (int j = 0; j < 4; ++j) {
        int i = base + j;
        if (i < N) {
            offsets[i] = running;
            cursor[i]  = running;
            running += v[j];
            if (i == N - 1) offsets[N] = running;   // = E
        }
    }
}

__global__ __launch_bounds__(256) void fill_csr_kernel(
    const int* __restrict__ edge_index, const int* __restrict__ edge_type,
    int* __restrict__ cursor, unsigned int* __restrict__ csr, int E)
{
    int e = blockIdx.x * 256 + threadIdx.x;
    if (e >= E) return;
    int dst = edge_index[E + e];
    int pos = atomicAdd(&cursor[dst], 1);
    csr[pos] = (unsigned int)edge_index[e] | ((unsigned int)edge_type[e] << 17);
}

// ---------------------------------------------------------------------------
// fused aggregate + finalize: one wave per node.
//   acc[h] = selfp[n][h] + sum_{e in CSR[n]} xp[type(e)][src(e)][h]
//   out[n] = W_out . relu(acc + b_self) + b_out
// No atomics; each edge message is one coalesced 128 B bf16 line.
// ---------------------------------------------------------------------------
__global__ __launch_bounds__(256) void agg_fin_kernel(
    const unsigned int* __restrict__ csr,
    const int* __restrict__ offsets,
    const unsigned short* __restrict__ xp,   // [8,N,64] bf16
    const float* __restrict__ selfp,         // [N,64]
    const float* __restrict__ b_self,        // [64]
    const float* __restrict__ W_out,         // [64]
    const float* __restrict__ b_out,         // [1]
    float* __restrict__ out,                 // [N]
    int N)
{
    int node = blockIdx.x * 4 + (threadIdx.x >> 6);
    int h    = threadIdx.x & 63;
    if (node >= N) return;
    int beg = offsets[node], end = offsets[node + 1];
    float acc = selfp[(size_t)node * HID + h];
    for (int e = beg; e < end; ++e) {
        unsigned int v = csr[e];
        int src = v & 0x1FFFF;
        int t   = v >> 17;
        acc += bf2f(xp[((size_t)t * N + src) * HID + h]);
    }
    acc = fmaxf(acc + b_self[h], 0.f);
    float p = acc * W_out[h];
    #pragma unroll
    for (int off = 32; off > 0; off >>= 1)
        p += __shfl_down(p, off, 64);
    if (h == 0) out[node] = p + b_out[0];
}

extern "C" void kernel_launch(void* const* d_in, const int* in_sizes, int n_in,
                              void* d_out, int out_size, void* d_ws, size_t ws_size,
                              hipStream_t stream)
{
    const float* x          = (const float*)d_in[0];
    const int*   edge_index = (const int*)  d_in[1];
    const int*   edge_type  = (const int*)  d_in[2];
    const float* W_rel      = (const float*)d_in[3];
    const float* b_rel      = (const float*)d_in[4];
    const float* W_self     = (const float*)d_in[5];
    const float* b_self     = (const float*)d_in[6];
    const float* W_out      = (const float*)d_in[7];
    const float* b_out      = (const float*)d_in[8];
    float* out = (float*)d_out;

    const int N = in_sizes[0] / IN_CH;   // 100000
    const int E = in_sizes[2];           // 600000

    // workspace layout (all 256 B aligned; ws_size known >= 230 MB from r1)
    char* w = (char*)d_ws;
    unsigned short* xp = (unsigned short*)w;            w += (size_t)N_REL * N * HID * 2;  // 102.4 MB
    float* selfp       = (float*)w;                     w += (size_t)N * HID * 4;          // 25.6 MB
    unsigned short* wpk= (unsigned short*)w;            w += (size_t)9 * 16 * 64 * 8 * 2;  // 147 KB
    int* cnt           = (int*)w;                       w += (size_t)N * 4;
    int* offsets       = (int*)w;                       w += (size_t)(N + 1) * 4 + 252;    // keep alignment
    int* cursor        = (int*)w;                       w += (size_t)N * 4;
    int* bsum          = (int*)w;                       w += 128 * 4;
    unsigned int* csr  = (unsigned int*)w;

    const int NB = (N + SCAN_E - 1) / SCAN_E;   // 98 (<=128 required)

    // 0) pack weights into MFMA fragment order (bf16)
    pack_w_kernel<<<36, 256, 0, stream>>>(W_rel, W_self, wpk);

    // 1) projections via bf16 MFMA (r==8 -> selfp; b_rel folded into xp)
    proj_mfma_kernel<<<(N + 127) / 128, 256, 0, stream>>>(x, wpk, b_rel,
                                                          xp, selfp, N);

    // 2) CSR build by dst
    hipMemsetAsync(cnt, 0, (size_t)N * 4, stream);
    hist_kernel<<<(E + 255) / 256, 256, 0, stream>>>(edge_index, cnt, E);
    scan_blocksum_kernel<<<NB, 256, 0, stream>>>(cnt, bsum, N);
    scan_partials_kernel<<<1, 128, 0, stream>>>(bsum, NB);
    scan_write_kernel<<<NB, 256, 0, stream>>>(cnt, bsum, offsets, cursor, N);
    fill_csr_kernel<<<(E + 255) / 256, 256, 0, stream>>>(edge_index, edge_type,
                                                         cursor, csr, E);

    // 3) fused aggregate + relu + output projection (no atomics)
    agg_fin_kernel<<<(N + 3) / 4, 256, 0, stream>>>(csr, offsets, xp, selfp,
                                                    b_self, W_out, b_out,
                                                    out, N);
}

// Round 5
// 276.943 us; speedup vs baseline: 1.7371x; 1.0833x over previous
//
#include <hip/hip_runtime.h>
#include <hip/hip_bf16.h>

#define IN_CH 128
#define HID   64
#define N_REL 8

using bf16x8 = __attribute__((ext_vector_type(8))) short;  // 8 bf16 (4 VGPRs)
using f32x4  = __attribute__((ext_vector_type(4))) float;

// float -> bf16 bits, round-to-nearest-even (finite inputs)
__device__ __forceinline__ short f2bf(float f) {
    unsigned int u = __float_as_uint(f);
    u += 0x7fffu + ((u >> 16) & 1u);
    return (short)(u >> 16);
}
__device__ __forceinline__ float bf2f(unsigned short b) {
    return __uint_as_float(((unsigned int)b) << 16);
}

// ---------------------------------------------------------------------------
// pack_w: rearrange the 9 weight matrices (8 rel + self) into bf16 MFMA
// fragment order (operand layout [row=lane&15][k=(lane>>4)*8+j]):
//   wpk[((r*16 + s*4 + t)*64 + lane)*8 + j]
//     = bf16( W_r[t*16 + (lane&15)][s*32 + (lane>>4)*8 + j] )
// 147 KB total — L2-resident for the whole proj pass.
// ---------------------------------------------------------------------------
__global__ __launch_bounds__(256) void pack_w_kernel(
    const float* __restrict__ W_rel,   // [8,64,128]
    const float* __restrict__ W_self,  // [64,128]
    unsigned short* __restrict__ wpk)  // [9*16*64*8]
{
    int gid = blockIdx.x * 256 + threadIdx.x;
    if (gid >= 9 * 16 * 64) return;
    int r    = gid >> 10;
    int f    = (gid >> 6) & 15;    // s*4 + t
    int lane = gid & 63;
    int s = f >> 2, t = f & 3;
    int row = t * 16 + (lane & 15);
    int col = s * 32 + (lane >> 4) * 8;
    const float* W = (r < N_REL) ? (W_rel + (size_t)r * HID * IN_CH) : W_self;
    const float* p = W + (size_t)row * IN_CH + col;
    float4 u0 = *(const float4*)p;
    float4 u1 = *(const float4*)(p + 4);
    bf16x8 b;
    b[0]=f2bf(u0.x); b[1]=f2bf(u0.y); b[2]=f2bf(u0.z); b[3]=f2bf(u0.w);
    b[4]=f2bf(u1.x); b[5]=f2bf(u1.y); b[6]=f2bf(u1.z); b[7]=f2bf(u1.w);
    *(bf16x8*)(wpk + (size_t)gid * 8) = b;
}

// ---------------------------------------------------------------------------
// proj (MFMA, A=W, B=x):
//   r<8:  xp[r][n][h] = bf16( x[n]·W_rel[r][h] + b_rel[r][h] )
//   r==8: xp[8][n][h] = bf16( x[n]·W_self[h] )           (self row, no bias)
// D layout: node = lane&15, h = t*16 + quad*4 + reg -> 8 B packed bf16 stores.
// Block = 64 nodes, 4 waves; each wave owns 16 nodes. 1563 blocks -> ~6
// blocks/CU (~24 waves/CU) for latency hiding (round-4 was 3 blocks/CU,
// latency-bound at 25% occupancy).
// ---------------------------------------------------------------------------
__global__ __launch_bounds__(256) void proj_mfma_kernel(
    const float* __restrict__ x,        // [N,128]
    const unsigned short* __restrict__ wpk,
    const float* __restrict__ b_rel,    // [8,64]
    unsigned short* __restrict__ xp,    // [9,N,64] bf16 bits
    int N)
{
    const int tid  = threadIdx.x;
    const int wave = tid >> 6;
    const int lane = tid & 63;
    const int l16  = lane & 15;
    const int quad = lane >> 4;
    const int nb   = blockIdx.x * 64 + wave * 16;   // wave's 16-node base
    const int node = nb + l16;

    // x fragments (B operand): xf[s] = x[node][s*32+quad*8 .. +7] as bf16
    bf16x8 xf[4];
    #pragma unroll
    for (int s = 0; s < 4; ++s) {
        float v[8] = {};
        if (node < N) {
            const float* p = x + (size_t)node * IN_CH + s * 32 + quad * 8;
            float4 u0 = *(const float4*)p;
            float4 u1 = *(const float4*)(p + 4);
            v[0]=u0.x; v[1]=u0.y; v[2]=u0.z; v[3]=u0.w;
            v[4]=u1.x; v[5]=u1.y; v[6]=u1.z; v[7]=u1.w;
        }
        bf16x8 a;
        #pragma unroll
        for (int j = 0; j < 8; ++j) a[j] = f2bf(v[j]);
        xf[s] = a;
    }

    const bf16x8* wv = (const bf16x8*)wpk;

    #pragma unroll 1
    for (int r = 0; r <= N_REL; ++r) {
        f32x4 acc[4];
        #pragma unroll
        for (int t = 0; t < 4; ++t) acc[t] = (f32x4){0.f, 0.f, 0.f, 0.f};

        #pragma unroll
        for (int s = 0; s < 4; ++s) {
            bf16x8 ws[4];
            #pragma unroll
            for (int t = 0; t < 4; ++t)
                ws[t] = wv[(size_t)((r * 16 + s * 4 + t) * 64) + lane];
            #pragma unroll
            for (int t = 0; t < 4; ++t)
                acc[t] = __builtin_amdgcn_mfma_f32_16x16x32_bf16(
                    ws[t], xf[s], acc[t], 0, 0, 0);
        }

        // epilogue: lane holds node, h = t*16 + quad*4 + i
        if (node < N) {
            #pragma unroll
            for (int t = 0; t < 4; ++t) {
                const int hb = t * 16 + quad * 4;
                float4 bias = make_float4(0.f, 0.f, 0.f, 0.f);
                if (r < N_REL) bias = *(const float4*)(b_rel + r * HID + hb);
                ushort4 u;
                u.x = (unsigned short)f2bf(acc[t][0] + bias.x);
                u.y = (unsigned short)f2bf(acc[t][1] + bias.y);
                u.z = (unsigned short)f2bf(acc[t][2] + bias.z);
                u.w = (unsigned short)f2bf(acc[t][3] + bias.w);
                *(ushort4*)(xp + ((size_t)r * N + node) * HID + hb) = u;
            }
        }
    }
}

// ---------------------------------------------------------------------------
// CSR build: histogram of dst -> exclusive scan -> fill packed edge list.
// CSR payload = precomputed xp element offset (t*N+src)*64 (fits u32).
// ---------------------------------------------------------------------------
__global__ __launch_bounds__(256) void hist_kernel(
    const int* __restrict__ edge_index, int* __restrict__ cnt, int E)
{
    int e = blockIdx.x * 256 + threadIdx.x;
    if (e < E) atomicAdd(&cnt[edge_index[E + e]], 1);
}

#define SCAN_E 1024   // elements per scan block (256 threads x 4)

__global__ __launch_bounds__(256) void scan_blocksum_kernel(
    const int* __restrict__ cnt, int* __restrict__ bsum, int N)
{
    __shared__ int s[256];
    int tid = threadIdx.x;
    int base = blockIdx.x * SCAN_E + tid * 4;
    int v = 0;
    #pragma unroll
    for (int j = 0; j < 4; ++j)
        if (base + j < N) v += cnt[base + j];
    s[tid] = v; __syncthreads();
    for (int off = 128; off > 0; off >>= 1) {
        if (tid < off) s[tid] += s[tid + off];
        __syncthreads();
    }
    if (tid == 0) bsum[blockIdx.x] = s[0];
}

__global__ __launch_bounds__(128) void scan_partials_kernel(
    int* __restrict__ bsum, int NB)   // NB <= 128
{
    __shared__ int s[128];
    int tid = threadIdx.x;
    int own = (tid < NB) ? bsum[tid] : 0;
    s[tid] = own; __syncthreads();
    for (int off = 1; off < 128; off <<= 1) {
        int v = (tid >= off) ? s[tid - off] : 0;
        __syncthreads();
        s[tid] += v;
        __syncthreads();
    }
    if (tid < NB) bsum[tid] = s[tid] - own;   // exclusive
}

__global__ __launch_bounds__(256) void scan_write_kernel(
    const int* __restrict__ cnt, const int* __restrict__ bsumx,
    int* __restrict__ offsets, int* __restrict__ cursor, int N)
{
    __shared__ int s[256];
    int tid = threadIdx.x;
    int base = blockIdx.x * SCAN_E + tid * 4;
    int v[4]; int sum = 0;
    #pragma unroll
    for (int j = 0; j < 4; ++j) {
        v[j] = (base + j < N) ? cnt[base + j] : 0;
        sum += v[j];
    }
    s[tid] = sum; __syncthreads();
    for (int off = 1; off < 256; off <<= 1) {
        int w = (tid >= off) ? s[tid - off] : 0;
        __syncthreads();
        s[tid] += w;
        __syncthreads();
    }
    int running = bsumx[blockIdx.x] + s[tid] - sum;   // exclusive up to base
    #pragma unroll
    for (int j = 0; j < 4; ++j) {
        int i = base + j;
        if (i < N) {
            offsets[i] = running;
            cursor[i]  = running;
            running += v[j];
            if (i == N - 1) offsets[N] = running;   // = E
        }
    }
}

__global__ __launch_bounds__(256) void fill_csr_kernel(
    const int* __restrict__ edge_index, const int* __restrict__ edge_type,
    int* __restrict__ cursor, unsigned int* __restrict__ csr, int E, int N)
{
    int e = blockIdx.x * 256 + threadIdx.x;
    if (e >= E) return;
    int dst = edge_index[E + e];
    unsigned int src = (unsigned int)edge_index[e];
    unsigned int t   = (unsigned int)edge_type[e];
    int pos = atomicAdd(&cursor[dst], 1);
    csr[pos] = (t * (unsigned int)N + src) * HID;   // element offset into xp
}

// ---------------------------------------------------------------------------
// fused aggregate + finalize: one wave per node.
//   acc[h] = xp[8][n][h] + sum_{e in CSR[n]} xp[csr[e]/64 ...][h]
//   out[n] = W_out . relu(acc + b_self) + b_out
// Edge loop unrolled x4: 4 independent 128 B gathers in flight per step.
// ---------------------------------------------------------------------------
__global__ __launch_bounds__(256) void agg_fin_kernel(
    const unsigned int* __restrict__ csr,
    const int* __restrict__ offsets,
    const unsigned short* __restrict__ xp,   // [9,N,64] bf16
    const float* __restrict__ b_self,        // [64]
    const float* __restrict__ W_out,         // [64]
    const float* __restrict__ b_out,         // [1]
    float* __restrict__ out,                 // [N]
    int N)
{
    int node = blockIdx.x * 4 + (threadIdx.x >> 6);
    int h    = threadIdx.x & 63;
    if (node >= N) return;
    int beg = offsets[node], end = offsets[node + 1];
    float acc = bf2f(xp[((size_t)N_REL * N + node) * HID + h]);   // self row
    int e = beg;
    #pragma unroll 1
    for (; e + 4 <= end; e += 4) {
        unsigned int v0 = csr[e + 0], v1 = csr[e + 1];
        unsigned int v2 = csr[e + 2], v3 = csr[e + 3];
        float m0 = bf2f(xp[(size_t)v0 + h]);
        float m1 = bf2f(xp[(size_t)v1 + h]);
        float m2 = bf2f(xp[(size_t)v2 + h]);
        float m3 = bf2f(xp[(size_t)v3 + h]);
        acc += m0; acc += m1; acc += m2; acc += m3;
    }
    for (; e < end; ++e)
        acc += bf2f(xp[(size_t)csr[e] + h]);
    acc = fmaxf(acc + b_self[h], 0.f);
    float p = acc * W_out[h];
    #pragma unroll
    for (int off = 32; off > 0; off >>= 1)
        p += __shfl_down(p, off, 64);
    if (h == 0) out[node] = p + b_out[0];
}

extern "C" void kernel_launch(void* const* d_in, const int* in_sizes, int n_in,
                              void* d_out, int out_size, void* d_ws, size_t ws_size,
                              hipStream_t stream)
{
    const float* x          = (const float*)d_in[0];
    const int*   edge_index = (const int*)  d_in[1];
    const int*   edge_type  = (const int*)  d_in[2];
    const float* W_rel      = (const float*)d_in[3];
    const float* b_rel      = (const float*)d_in[4];
    const float* W_self     = (const float*)d_in[5];
    const float* b_self     = (const float*)d_in[6];
    const float* W_out      = (const float*)d_in[7];
    const float* b_out      = (const float*)d_in[8];
    float* out = (float*)d_out;

    const int N = in_sizes[0] / IN_CH;   // 100000
    const int E = in_sizes[2];           // 600000

    // workspace layout (256 B aligned)
    char* w = (char*)d_ws;
    unsigned short* xp = (unsigned short*)w;            // [9,N,64] bf16, 115.2 MB
    w += (size_t)(N_REL + 1) * N * HID * 2;
    unsigned short* wpk = (unsigned short*)w;           // 147 KB
    w += (size_t)9 * 16 * 64 * 8 * 2;
    int* cnt     = (int*)w;  w += (size_t)N * 4;
    int* offsets = (int*)w;  w += (size_t)(N + 1) * 4 + 252;
    int* cursor  = (int*)w;  w += (size_t)N * 4;
    int* bsum    = (int*)w;  w += 128 * 4;
    unsigned int* csr = (unsigned int*)w;               // [E] u32, 2.4 MB

    const int NB = (N + SCAN_E - 1) / SCAN_E;   // 98 (<=128 required)

    // 0) pack weights into MFMA fragment order (bf16)
    pack_w_kernel<<<36, 256, 0, stream>>>(W_rel, W_self, wpk);

    // 1) projections via bf16 MFMA (r==8 = self row; b_rel folded into xp)
    proj_mfma_kernel<<<(N + 63) / 64, 256, 0, stream>>>(x, wpk, b_rel, xp, N);

    // 2) CSR build by dst (payload = precomputed xp element offset)
    hipMemsetAsync(cnt, 0, (size_t)N * 4, stream);
    hist_kernel<<<(E + 255) / 256, 256, 0, stream>>>(edge_index, cnt, E);
    scan_blocksum_kernel<<<NB, 256, 0, stream>>>(cnt, bsum, N);
    scan_partials_kernel<<<1, 128, 0, stream>>>(bsum, NB);
    scan_write_kernel<<<NB, 256, 0, stream>>>(cnt, bsum, offsets, cursor, N);
    fill_csr_kernel<<<(E + 255) / 256, 256, 0, stream>>>(edge_index, edge_type,
                                                         cursor, csr, E, N);

    // 3) fused aggregate + relu + output projection (no atomics)
    agg_fin_kernel<<<(N + 3) / 4, 256, 0, stream>>>(csr, offsets, xp,
                                                    b_self, W_out, b_out,
                                                    out, N);
}

// Round 6
// 262.045 us; speedup vs baseline: 1.8359x; 1.0569x over previous
//
#include <hip/hip_runtime.h>
#include <hip/hip_bf16.h>

#define IN_CH 128
#define HID   64
#define N_REL 8
#define TPW   8      // node-tiles (of 16) per wave in proj

using bf16x8 = __attribute__((ext_vector_type(8))) short;  // 8 bf16 (4 VGPRs)
using f32x4  = __attribute__((ext_vector_type(4))) float;

// float -> bf16 bits, round-to-nearest-even (finite inputs)
__device__ __forceinline__ short f2bf(float f) {
    unsigned int u = __float_as_uint(f);
    u += 0x7fffu + ((u >> 16) & 1u);
    return (short)(u >> 16);
}
__device__ __forceinline__ float bf2f(unsigned short b) {
    return __uint_as_float(((unsigned int)b) << 16);
}

// ---------------------------------------------------------------------------
// x2bf: stream-convert x [N,128] fp32 -> xb [N,128] bf16 (row-major).
// One thread = 8 elements; fully coalesced both sides.
// ---------------------------------------------------------------------------
__global__ __launch_bounds__(256) void x2bf_kernel(
    const float* __restrict__ x, unsigned short* __restrict__ xb, int total8)
{
    int i = blockIdx.x * 256 + threadIdx.x;
    if (i >= total8) return;
    const float* p = x + (size_t)i * 8;
    float4 a = *(const float4*)p;
    float4 b = *(const float4*)(p + 4);
    bf16x8 o;
    o[0]=f2bf(a.x); o[1]=f2bf(a.y); o[2]=f2bf(a.z); o[3]=f2bf(a.w);
    o[4]=f2bf(b.x); o[5]=f2bf(b.y); o[6]=f2bf(b.z); o[7]=f2bf(b.w);
    *(bf16x8*)(xb + (size_t)i * 8) = o;
}

// ---------------------------------------------------------------------------
// pack_w: 9 weight matrices (8 rel + self) -> bf16 MFMA fragment order:
//   wpk[((r*16 + s*4 + t)*64 + lane)*8 + j]
//     = bf16( W_r[t*16 + (lane&15)][s*32 + (lane>>4)*8 + j] )
// ---------------------------------------------------------------------------
__global__ __launch_bounds__(256) void pack_w_kernel(
    const float* __restrict__ W_rel,   // [8,64,128]
    const float* __restrict__ W_self,  // [64,128]
    unsigned short* __restrict__ wpk)  // [9*16*64*8]
{
    int gid = blockIdx.x * 256 + threadIdx.x;
    if (gid >= 9 * 16 * 64) return;
    int r    = gid >> 10;
    int f    = (gid >> 6) & 15;    // s*4 + t
    int lane = gid & 63;
    int s = f >> 2, t = f & 3;
    int row = t * 16 + (lane & 15);
    int col = s * 32 + (lane >> 4) * 8;
    const float* W = (r < N_REL) ? (W_rel + (size_t)r * HID * IN_CH) : W_self;
    const float* p = W + (size_t)row * IN_CH + col;
    float4 u0 = *(const float4*)p;
    float4 u1 = *(const float4*)(p + 4);
    bf16x8 b;
    b[0]=f2bf(u0.x); b[1]=f2bf(u0.y); b[2]=f2bf(u0.z); b[3]=f2bf(u0.w);
    b[4]=f2bf(u1.x); b[5]=f2bf(u1.y); b[6]=f2bf(u1.z); b[7]=f2bf(u1.w);
    *(bf16x8*)(wpk + (size_t)gid * 8) = b;
}

// ---------------------------------------------------------------------------
// proj (MFMA, A=W, B=x). grid = (node-chunks, 9 relations).
// Each wave: load its relation's 16 weight fragments ONCE into registers
// (64 VGPRs), then stream TPW 16-node tiles: 4 xb loads + 16 MFMA + 4 stores.
// D layout: node = lane&15, h = t*16 + quad*4 + reg.
//   r<8:  xp[r][n][h] = bf16( x[n]·W_rel[r][h] + b_rel[r][h] )
//   r==8: xp[8][n][h] = bf16( x[n]·W_self[h] )
// N is a multiple of 16 (100000 = 6250*16) -> no per-node guards.
// ---------------------------------------------------------------------------
__global__ __launch_bounds__(256) void proj_mfma_kernel(
    const unsigned short* __restrict__ xb,   // [N,128] bf16
    const unsigned short* __restrict__ wpk,  // fragment-packed weights
    const float* __restrict__ b_rel,         // [8,64]
    unsigned short* __restrict__ xp,         // [9,N,64] bf16
    int N)
{
    const int tid  = threadIdx.x;
    const int wave = tid >> 6;
    const int lane = tid & 63;
    const int l16  = lane & 15;
    const int quad = lane >> 4;
    const int r    = blockIdx.y;

    // weights for this relation: held in registers for the whole kernel
    const bf16x8* wv = (const bf16x8*)wpk;
    bf16x8 ws[16];
    #pragma unroll
    for (int f = 0; f < 16; ++f)
        ws[f] = wv[(size_t)((r * 16 + f) * 64) + lane];

    // bias (loop-invariant): lane's h-base for t is t*16 + quad*4
    float4 bias[4];
    #pragma unroll
    for (int t = 0; t < 4; ++t)
        bias[t] = (r < N_REL)
            ? *(const float4*)(b_rel + r * HID + t * 16 + quad * 4)
            : make_float4(0.f, 0.f, 0.f, 0.f);

    const int NT = N >> 4;                       // 6250 tiles
    const int g0 = blockIdx.x * (4 * TPW) + wave * TPW;

    for (int i = 0; i < TPW; ++i) {
        const int g = g0 + i;
        if (g >= NT) break;
        const int node = g * 16 + l16;

        // x fragments: xf[s] = xb[node][s*32 + quad*8 .. +7] (16 B each)
        const unsigned short* xr = xb + (size_t)node * IN_CH + quad * 8;
        bf16x8 xf[4];
        #pragma unroll
        for (int s = 0; s < 4; ++s)
            xf[s] = *(const bf16x8*)(xr + s * 32);

        f32x4 acc[4];
        #pragma unroll
        for (int t = 0; t < 4; ++t) acc[t] = (f32x4){0.f, 0.f, 0.f, 0.f};

        #pragma unroll
        for (int s = 0; s < 4; ++s)
            #pragma unroll
            for (int t = 0; t < 4; ++t)
                acc[t] = __builtin_amdgcn_mfma_f32_16x16x32_bf16(
                    ws[s * 4 + t], xf[s], acc[t], 0, 0, 0);

        unsigned short* orow = xp + ((size_t)r * N + node) * HID;
        #pragma unroll
        for (int t = 0; t < 4; ++t) {
            ushort4 u;
            u.x = (unsigned short)f2bf(acc[t][0] + bias[t].x);
            u.y = (unsigned short)f2bf(acc[t][1] + bias[t].y);
            u.z = (unsigned short)f2bf(acc[t][2] + bias[t].z);
            u.w = (unsigned short)f2bf(acc[t][3] + bias[t].w);
            *(ushort4*)(orow + t * 16 + quad * 4) = u;
        }
    }
}

// ---------------------------------------------------------------------------
// CSR build: histogram of dst -> exclusive scan -> fill packed edge list.
// CSR payload = precomputed xp element offset (t*N+src)*64 (fits u32).
// ---------------------------------------------------------------------------
__global__ __launch_bounds__(256) void hist_kernel(
    const int* __restrict__ edge_index, int* __restrict__ cnt, int E)
{
    int e = blockIdx.x * 256 + threadIdx.x;
    if (e < E) atomicAdd(&cnt[edge_index[E + e]], 1);
}

#define SCAN_E 1024   // elements per scan block (256 threads x 4)

__global__ __launch_bounds__(256) void scan_blocksum_kernel(
    const int* __restrict__ cnt, int* __restrict__ bsum, int N)
{
    __shared__ int s[256];
    int tid = threadIdx.x;
    int base = blockIdx.x * SCAN_E + tid * 4;
    int v = 0;
    #pragma unroll
    for (int j = 0; j < 4; ++j)
        if (base + j < N) v += cnt[base + j];
    s[tid] = v; __syncthreads();
    for (int off = 128; off > 0; off >>= 1) {
        if (tid < off) s[tid] += s[tid + off];
        __syncthreads();
    }
    if (tid == 0) bsum[blockIdx.x] = s[0];
}

__global__ __launch_bounds__(128) void scan_partials_kernel(
    int* __restrict__ bsum, int NB)   // NB <= 128
{
    __shared__ int s[128];
    int tid = threadIdx.x;
    int own = (tid < NB) ? bsum[tid] : 0;
    s[tid] = own; __syncthreads();
    for (int off = 1; off < 128; off <<= 1) {
        int v = (tid >= off) ? s[tid - off] : 0;
        __syncthreads();
        s[tid] += v;
        __syncthreads();
    }
    if (tid < NB) bsum[tid] = s[tid] - own;   // exclusive
}

__global__ __launch_bounds__(256) void scan_write_kernel(
    const int* __restrict__ cnt, const int* __restrict__ bsumx,
    int* __restrict__ offsets, int* __restrict__ cursor, int N)
{
    __shared__ int s[256];
    int tid = threadIdx.x;
    int base = blockIdx.x * SCAN_E + tid * 4;
    int v[4]; int sum = 0;
    #pragma unroll
    for (int j = 0; j < 4; ++j) {
        v[j] = (base + j < N) ? cnt[base + j] : 0;
        sum += v[j];
    }
    s[tid] = sum; __syncthreads();
    for (int off = 1; off < 256; off <<= 1) {
        int w = (tid >= off) ? s[tid - off] : 0;
        __syncthreads();
        s[tid] += w;
        __syncthreads();
    }
    int running = bsumx[blockIdx.x] + s[tid] - sum;   // exclusive up to base
    #pragma unroll
    for (int j = 0; j < 4; ++j) {
        int i = base + j;
        if (i < N) {
            offsets[i] = running;
            cursor[i]  = running;
            running += v[j];
            if (i == N - 1) offsets[N] = running;   // = E
        }
    }
}

__global__ __launch_bounds__(256) void fill_csr_kernel(
    const int* __restrict__ edge_index, const int* __restrict__ edge_type,
    int* __restrict__ cursor, unsigned int* __restrict__ csr, int E, int N)
{
    int e = blockIdx.x * 256 + threadIdx.x;
    if (e >= E) return;
    int dst = edge_index[E + e];
    unsigned int src = (unsigned int)edge_index[e];
    unsigned int t   = (unsigned int)edge_type[e];
    int pos = atomicAdd(&cursor[dst], 1);
    csr[pos] = (t * (unsigned int)N + src) * HID;   // element offset into xp
}

// ---------------------------------------------------------------------------
// fused aggregate + finalize: one wave per node.
//   acc[h] = xp[8][n][h] + sum_{e in CSR[n]} xp[csr[e] + h]
//   out[n] = W_out . relu(acc + b_self) + b_out
// Edge loop unrolled x8/x4 for MLP (each gather = one 128 B line).
// ---------------------------------------------------------------------------
__global__ __launch_bounds__(256) void agg_fin_kernel(
    const unsigned int* __restrict__ csr,
    const int* __restrict__ offsets,
    const unsigned short* __restrict__ xp,   // [9,N,64] bf16
    const float* __restrict__ b_self,        // [64]
    const float* __restrict__ W_out,         // [64]
    const float* __restrict__ b_out,         // [1]
    float* __restrict__ out,                 // [N]
    int N)
{
    int node = blockIdx.x * 4 + (threadIdx.x >> 6);
    int h    = threadIdx.x & 63;
    if (node >= N) return;
    int beg = offsets[node], end = offsets[node + 1];
    float acc = bf2f(xp[((size_t)N_REL * N + node) * HID + h]);   // self row
    int e = beg;
    #pragma unroll 1
    for (; e + 8 <= end; e += 8) {
        unsigned int v0 = csr[e+0], v1 = csr[e+1], v2 = csr[e+2], v3 = csr[e+3];
        unsigned int v4 = csr[e+4], v5 = csr[e+5], v6 = csr[e+6], v7 = csr[e+7];
        float m0 = bf2f(xp[(size_t)v0 + h]);
        float m1 = bf2f(xp[(size_t)v1 + h]);
        float m2 = bf2f(xp[(size_t)v2 + h]);
        float m3 = bf2f(xp[(size_t)v3 + h]);
        float m4 = bf2f(xp[(size_t)v4 + h]);
        float m5 = bf2f(xp[(size_t)v5 + h]);
        float m6 = bf2f(xp[(size_t)v6 + h]);
        float m7 = bf2f(xp[(size_t)v7 + h]);
        acc += ((m0 + m1) + (m2 + m3)) + ((m4 + m5) + (m6 + m7));
    }
    #pragma unroll 1
    for (; e + 4 <= end; e += 4) {
        unsigned int v0 = csr[e+0], v1 = csr[e+1], v2 = csr[e+2], v3 = csr[e+3];
        float m0 = bf2f(xp[(size_t)v0 + h]);
        float m1 = bf2f(xp[(size_t)v1 + h]);
        float m2 = bf2f(xp[(size_t)v2 + h]);
        float m3 = bf2f(xp[(size_t)v3 + h]);
        acc += (m0 + m1) + (m2 + m3);
    }
    for (; e < end; ++e)
        acc += bf2f(xp[(size_t)csr[e] + h]);
    acc = fmaxf(acc + b_self[h], 0.f);
    float p = acc * W_out[h];
    #pragma unroll
    for (int off = 32; off > 0; off >>= 1)
        p += __shfl_down(p, off, 64);
    if (h == 0) out[node] = p + b_out[0];
}

extern "C" void kernel_launch(void* const* d_in, const int* in_sizes, int n_in,
                              void* d_out, int out_size, void* d_ws, size_t ws_size,
                              hipStream_t stream)
{
    const float* x          = (const float*)d_in[0];
    const int*   edge_index = (const int*)  d_in[1];
    const int*   edge_type  = (const int*)  d_in[2];
    const float* W_rel      = (const float*)d_in[3];
    const float* b_rel      = (const float*)d_in[4];
    const float* W_self     = (const float*)d_in[5];
    const float* b_self     = (const float*)d_in[6];
    const float* W_out      = (const float*)d_in[7];
    const float* b_out      = (const float*)d_in[8];
    float* out = (float*)d_out;

    const int N = in_sizes[0] / IN_CH;   // 100000 (multiple of 16)
    const int E = in_sizes[2];           // 600000

    // workspace layout (256 B aligned)
    char* w = (char*)d_ws;
    unsigned short* xp = (unsigned short*)w;            // [9,N,64] bf16, 115.2 MB
    w += (size_t)(N_REL + 1) * N * HID * 2;
    unsigned short* xb = (unsigned short*)w;            // [N,128] bf16, 25.6 MB
    w += (size_t)N * IN_CH * 2;
    unsigned short* wpk = (unsigned short*)w;           // 147 KB
    w += (size_t)9 * 16 * 64 * 8 * 2;
    int* cnt     = (int*)w;  w += (size_t)N * 4;
    int* offsets = (int*)w;  w += (size_t)(N + 1) * 4 + 252;
    int* cursor  = (int*)w;  w += (size_t)N * 4;
    int* bsum    = (int*)w;  w += 128 * 4;
    unsigned int* csr = (unsigned int*)w;               // [E] u32, 2.4 MB

    const int NB = (N + SCAN_E - 1) / SCAN_E;   // 98 (<=128 required)

    // 0) one-shot preps: weights -> fragment order; x -> bf16
    pack_w_kernel<<<36, 256, 0, stream>>>(W_rel, W_self, wpk);
    x2bf_kernel<<<(N * IN_CH / 8 + 255) / 256, 256, 0, stream>>>(
        x, xb, N * IN_CH / 8);

    // 1) CSR build by dst (payload = precomputed xp element offset)
    hipMemsetAsync(cnt, 0, (size_t)N * 4, stream);
    hist_kernel<<<(E + 255) / 256, 256, 0, stream>>>(edge_index, cnt, E);
    scan_blocksum_kernel<<<NB, 256, 0, stream>>>(cnt, bsum, N);
    scan_partials_kernel<<<1, 128, 0, stream>>>(bsum, NB);
    scan_write_kernel<<<NB, 256, 0, stream>>>(cnt, bsum, offsets, cursor, N);
    fill_csr_kernel<<<(E + 255) / 256, 256, 0, stream>>>(edge_index, edge_type,
                                                         cursor, csr, E, N);

    // 2) projections: weights-in-registers, stream nodes
    const int NT = N / 16;                         // 6250 tiles
    dim3 pgrid((NT + 4 * TPW - 1) / (4 * TPW), N_REL + 1);   // (196, 9)
    proj_mfma_kernel<<<pgrid, 256, 0, stream>>>(xb, wpk, b_rel, xp, N);

    // 3) fused aggregate + relu + output projection (no atomics)
    agg_fin_kernel<<<(N + 3) / 4, 256, 0, stream>>>(csr, offsets, xp,
                                                    b_self, W_out, b_out,
                                                    out, N);
}